// Round 1
// baseline (6215.374 us; speedup 1.0000x reference)
//
#include <hip/hip_runtime.h>
#include <hip/hip_bf16.h>

#define B_ 4
#define N_ 2048
#define D_ 512
#define H_ 8
#define DH_ 64
#define DFF_ 2048
#define ROWS_ (B_ * N_)   // 8192

// ---------------------------------------------------------------------------
// LayerNorm: one wave (64 lanes) per row of 512 floats. 4 rows per block.
// ---------------------------------------------------------------------------
__global__ __launch_bounds__(256) void ln_kernel(const float* __restrict__ x,
                                                 const float* __restrict__ g,
                                                 const float* __restrict__ b,
                                                 float* __restrict__ out) {
    int wave = threadIdx.x >> 6;
    int lane = threadIdx.x & 63;
    int row  = blockIdx.x * 4 + wave;
    const float* xr = x + (size_t)row * D_;

    float4 v0 = ((const float4*)xr)[lane * 2 + 0];
    float4 v1 = ((const float4*)xr)[lane * 2 + 1];

    float s = v0.x + v0.y + v0.z + v0.w + v1.x + v1.y + v1.z + v1.w;
    #pragma unroll
    for (int off = 32; off; off >>= 1) s += __shfl_xor(s, off, 64);
    float mu = s * (1.0f / D_);

    float d0 = v0.x - mu, d1 = v0.y - mu, d2 = v0.z - mu, d3 = v0.w - mu;
    float d4 = v1.x - mu, d5 = v1.y - mu, d6 = v1.z - mu, d7 = v1.w - mu;
    float vs = d0*d0 + d1*d1 + d2*d2 + d3*d3 + d4*d4 + d5*d5 + d6*d6 + d7*d7;
    #pragma unroll
    for (int off = 32; off; off >>= 1) vs += __shfl_xor(vs, off, 64);
    float rstd = rsqrtf(vs * (1.0f / D_) + 1e-5f);

    float4 g0 = ((const float4*)g)[lane * 2 + 0];
    float4 g1 = ((const float4*)g)[lane * 2 + 1];
    float4 b0 = ((const float4*)b)[lane * 2 + 0];
    float4 b1 = ((const float4*)b)[lane * 2 + 1];

    float4 o0, o1;
    o0.x = d0 * rstd * g0.x + b0.x;  o0.y = d1 * rstd * g0.y + b0.y;
    o0.z = d2 * rstd * g0.z + b0.z;  o0.w = d3 * rstd * g0.w + b0.w;
    o1.x = d4 * rstd * g1.x + b1.x;  o1.y = d5 * rstd * g1.y + b1.y;
    o1.z = d6 * rstd * g1.z + b1.z;  o1.w = d7 * rstd * g1.w + b1.w;

    float* outr = out + (size_t)row * D_;
    ((float4*)outr)[lane * 2 + 0] = o0;
    ((float4*)outr)[lane * 2 + 1] = o1;
}

// ---------------------------------------------------------------------------
// fp32 tiled GEMM: C[M,N] = A[M,K] @ W[K,N] + bias (+resid) (+gelu)
// 64x64 tile, BK=16, 256 threads, 4x4 accum per thread.
// M,N multiples of 64; K multiple of 16 (true for all shapes here).
// ---------------------------------------------------------------------------
template<bool GELU, bool RESID>
__global__ __launch_bounds__(256) void gemm_kernel(const float* __restrict__ A,
                                                   const float* __restrict__ W,
                                                   const float* __restrict__ bias,
                                                   const float* __restrict__ resid,
                                                   float* __restrict__ C,
                                                   int M, int N, int K) {
    __shared__ float As[16][65];  // As[k][row]
    __shared__ float Ws[16][68];  // Ws[k][col]

    int tid = threadIdx.x;
    int tx = tid & 15;        // col group
    int ty = tid >> 4;        // row group
    int row0 = blockIdx.y * 64;
    int col0 = blockIdx.x * 64;

    float acc[4][4] = {};

    for (int k0 = 0; k0 < K; k0 += 16) {
        // A tile: 64 rows x 16 k. One float4 (along K) per thread.
        {
            int r  = tid >> 2;          // 0..63
            int kq = (tid & 3) * 4;     // 0,4,8,12
            float4 a = *(const float4*)&A[(size_t)(row0 + r) * K + k0 + kq];
            As[kq + 0][r] = a.x;
            As[kq + 1][r] = a.y;
            As[kq + 2][r] = a.z;
            As[kq + 3][r] = a.w;
        }
        // W tile: 16 k x 64 cols. One float4 (along N) per thread.
        {
            int kr = tid >> 4;          // 0..15
            int cq = (tid & 15) * 4;    // 0..60
            float4 w = *(const float4*)&W[(size_t)(k0 + kr) * N + col0 + cq];
            *(float4*)&Ws[kr][cq] = w;
        }
        __syncthreads();

        #pragma unroll
        for (int k = 0; k < 16; ++k) {
            float a[4], w[4];
            #pragma unroll
            for (int i = 0; i < 4; ++i) a[i] = As[k][ty * 4 + i];
            #pragma unroll
            for (int j = 0; j < 4; ++j) w[j] = Ws[k][tx * 4 + j];
            #pragma unroll
            for (int i = 0; i < 4; ++i)
                #pragma unroll
                for (int j = 0; j < 4; ++j)
                    acc[i][j] += a[i] * w[j];
        }
        __syncthreads();
    }

    // epilogue
    float4 bi = *(const float4*)&bias[col0 + tx * 4];
    #pragma unroll
    for (int i = 0; i < 4; ++i) {
        int row = row0 + ty * 4 + i;
        size_t base = (size_t)row * N + col0 + tx * 4;
        float v[4] = {acc[i][0] + bi.x, acc[i][1] + bi.y,
                      acc[i][2] + bi.z, acc[i][3] + bi.w};
        if (RESID) {
            float4 r = *(const float4*)&resid[base];
            v[0] += r.x; v[1] += r.y; v[2] += r.z; v[3] += r.w;
        }
        if (GELU) {
            #pragma unroll
            for (int j = 0; j < 4; ++j)
                v[j] = 0.5f * v[j] * (1.0f + erff(v[j] * 0.70710678118654752f));
        }
        float4 o = {v[0], v[1], v[2], v[3]};
        *(float4*)&C[base] = o;
    }
}

// ---------------------------------------------------------------------------
// Attention: one block per (b, h, query row n). Scores row kept in LDS.
// qkv layout from GEMM: [row = b*N+n][3*D] with col = which*512 + h*64 + dh
// out layout: [b*N+n][h*64 + dh]  (i.e. (B,N,D))
// ---------------------------------------------------------------------------
__global__ __launch_bounds__(256) void attn_kernel(const float* __restrict__ qkv,
                                                   float* __restrict__ out) {
    __shared__ float q[DH_];
    __shared__ float sc[N_];
    __shared__ float redmax[4];
    __shared__ float redsum[4];
    __shared__ float po[4][DH_];

    int idx = blockIdx.x;
    int n = idx & (N_ - 1);
    int h = (idx >> 11) & (H_ - 1);
    int b = idx >> 14;

    int tid  = threadIdx.x;
    int lane = tid & 63;
    int wave = tid >> 6;

    const float scale = 0.125f;  // 1/sqrt(64)
    const size_t rowbase = (size_t)(b * N_ + n) * (3 * D_);

    if (tid < DH_) q[tid] = qkv[rowbase + h * DH_ + tid];
    __syncthreads();

    // scores
    for (int m = tid; m < N_; m += 256) {
        const float* kp = &qkv[(size_t)(b * N_ + m) * (3 * D_) + D_ + h * DH_];
        float s = 0.0f;
        #pragma unroll
        for (int d = 0; d < DH_; d += 4) {
            float4 kv = *(const float4*)&kp[d];
            s += q[d] * kv.x + q[d + 1] * kv.y + q[d + 2] * kv.z + q[d + 3] * kv.w;
        }
        sc[m] = s * scale;
    }
    __syncthreads();

    // row max
    float mx = -3.402823466e+38f;
    for (int m = tid; m < N_; m += 256) mx = fmaxf(mx, sc[m]);
    #pragma unroll
    for (int off = 32; off; off >>= 1) mx = fmaxf(mx, __shfl_xor(mx, off, 64));
    if (lane == 0) redmax[wave] = mx;
    __syncthreads();
    float rowmax = fmaxf(fmaxf(redmax[0], redmax[1]), fmaxf(redmax[2], redmax[3]));

    // exp + sum
    float sum = 0.0f;
    for (int m = tid; m < N_; m += 256) {
        float e = __expf(sc[m] - rowmax);
        sc[m] = e;
        sum += e;
    }
    #pragma unroll
    for (int off = 32; off; off >>= 1) sum += __shfl_xor(sum, off, 64);
    if (lane == 0) redsum[wave] = sum;
    __syncthreads();
    float inv = 1.0f / (redsum[0] + redsum[1] + redsum[2] + redsum[3]);

    // out[d] = sum_m p[m] * v[m][d]
    int d     = tid & (DH_ - 1);
    int chunk = tid >> 6;  // 4 chunks of 512 m each
    float acc = 0.0f;
    int m0 = chunk * (N_ / 4), m1 = m0 + (N_ / 4);
    for (int m = m0; m < m1; ++m) {
        acc += sc[m] * qkv[(size_t)(b * N_ + m) * (3 * D_) + 2 * D_ + h * DH_ + d];
    }
    po[chunk][d] = acc;
    __syncthreads();

    if (tid < DH_) {
        float o = (po[0][tid] + po[1][tid] + po[2][tid] + po[3][tid]) * inv;
        out[(size_t)(b * N_ + n) * D_ + h * DH_ + tid] = o;
    }
}

// ---------------------------------------------------------------------------
extern "C" void kernel_launch(void* const* d_in, const int* in_sizes, int n_in,
                              void* d_out, int out_size, void* d_ws, size_t ws_size,
                              hipStream_t stream) {
    const float* x      = (const float*)d_in[0];
    const float* ln1_g  = (const float*)d_in[1];
    const float* ln1_b  = (const float*)d_in[2];
    const float* Wqkv   = (const float*)d_in[3];
    const float* bqkv   = (const float*)d_in[4];
    const float* Wproj  = (const float*)d_in[5];
    const float* bproj  = (const float*)d_in[6];
    const float* ln2_g  = (const float*)d_in[7];
    const float* ln2_b  = (const float*)d_in[8];
    const float* W1     = (const float*)d_in[9];
    const float* b1     = (const float*)d_in[10];
    const float* W2     = (const float*)d_in[11];
    const float* b2     = (const float*)d_in[12];
    float* out = (float*)d_out;

    float* ws = (float*)d_ws;
    // offsets in floats (with reuse):
    float* h       = ws + 0;                       // 8192*512  = 4,194,304
    float* qkv     = ws + 4194304;                 // 8192*1536 = 12,582,912
    float* attnout = ws + 0;                       // reuse h slot
    float* x2      = ws + 16777216;                // 8192*512
    float* h2      = ws + 0;                       // reuse attnout slot
    float* ffh     = ws + 20971520;                // 8192*2048 = 16,777,216
    // peak: 37,748,736 floats = 151 MB

    dim3 blk(256);

    // 1. h = LN1(x)
    ln_kernel<<<ROWS_ / 4, blk, 0, stream>>>(x, ln1_g, ln1_b, h);

    // 2. qkv = h @ Wqkv + bqkv           [8192,512]x[512,1536]
    gemm_kernel<false, false><<<dim3(1536 / 64, ROWS_ / 64), blk, 0, stream>>>(
        h, Wqkv, bqkv, nullptr, qkv, ROWS_, 1536, 512);

    // 3. attnout = softmax(qk^T)v
    attn_kernel<<<B_ * H_ * N_, blk, 0, stream>>>(qkv, attnout);

    // 4. x2 = x + attnout @ Wproj + bproj
    gemm_kernel<false, true><<<dim3(512 / 64, ROWS_ / 64), blk, 0, stream>>>(
        attnout, Wproj, bproj, x, x2, ROWS_, 512, 512);

    // 5. h2 = LN2(x2)
    ln_kernel<<<ROWS_ / 4, blk, 0, stream>>>(x2, ln2_g, ln2_b, h2);

    // 6. ffh = gelu(h2 @ W1 + b1)        [8192,512]x[512,2048]
    gemm_kernel<true, false><<<dim3(2048 / 64, ROWS_ / 64), blk, 0, stream>>>(
        h2, W1, b1, nullptr, ffh, ROWS_, 2048, 512);

    // 7. out = x2 + ffh @ W2 + b2        [8192,2048]x[2048,512]
    gemm_kernel<false, true><<<dim3(512 / 64, ROWS_ / 64), blk, 0, stream>>>(
        ffh, W2, b2, x2, out, ROWS_, 512, 2048);
}

// Round 2
// 1385.528 us; speedup vs baseline: 4.4859x; 4.4859x over previous
//
#include <hip/hip_runtime.h>
#include <hip/hip_bf16.h>

#define B_ 4
#define N_ 2048
#define D_ 512
#define H_ 8
#define DH_ 64
#define DFF_ 2048
#define ROWS_ (B_ * N_)   // 8192

// ---------------------------------------------------------------------------
// LayerNorm: one wave (64 lanes) per row of 512 floats. 4 rows per block.
// ---------------------------------------------------------------------------
__global__ __launch_bounds__(256) void ln_kernel(const float* __restrict__ x,
                                                 const float* __restrict__ g,
                                                 const float* __restrict__ b,
                                                 float* __restrict__ out) {
    int wave = threadIdx.x >> 6;
    int lane = threadIdx.x & 63;
    int row  = blockIdx.x * 4 + wave;
    const float* xr = x + (size_t)row * D_;

    float4 v0 = ((const float4*)xr)[lane * 2 + 0];
    float4 v1 = ((const float4*)xr)[lane * 2 + 1];

    float s = v0.x + v0.y + v0.z + v0.w + v1.x + v1.y + v1.z + v1.w;
    #pragma unroll
    for (int off = 32; off; off >>= 1) s += __shfl_xor(s, off, 64);
    float mu = s * (1.0f / D_);

    float d0 = v0.x - mu, d1 = v0.y - mu, d2 = v0.z - mu, d3 = v0.w - mu;
    float d4 = v1.x - mu, d5 = v1.y - mu, d6 = v1.z - mu, d7 = v1.w - mu;
    float vs = d0*d0 + d1*d1 + d2*d2 + d3*d3 + d4*d4 + d5*d5 + d6*d6 + d7*d7;
    #pragma unroll
    for (int off = 32; off; off >>= 1) vs += __shfl_xor(vs, off, 64);
    float rstd = rsqrtf(vs * (1.0f / D_) + 1e-5f);

    float4 g0 = ((const float4*)g)[lane * 2 + 0];
    float4 g1 = ((const float4*)g)[lane * 2 + 1];
    float4 b0 = ((const float4*)b)[lane * 2 + 0];
    float4 b1 = ((const float4*)b)[lane * 2 + 1];

    float4 o0, o1;
    o0.x = d0 * rstd * g0.x + b0.x;  o0.y = d1 * rstd * g0.y + b0.y;
    o0.z = d2 * rstd * g0.z + b0.z;  o0.w = d3 * rstd * g0.w + b0.w;
    o1.x = d4 * rstd * g1.x + b1.x;  o1.y = d5 * rstd * g1.y + b1.y;
    o1.z = d6 * rstd * g1.z + b1.z;  o1.w = d7 * rstd * g1.w + b1.w;

    float* outr = out + (size_t)row * D_;
    ((float4*)outr)[lane * 2 + 0] = o0;
    ((float4*)outr)[lane * 2 + 1] = o1;
}

// ---------------------------------------------------------------------------
// fp32 tiled GEMM: C[M,N] = A[M,K] @ W[K,N] + bias (+resid) (+gelu)
// 64x64 tile, BK=16, 256 threads, 4x4 accum per thread.
// ---------------------------------------------------------------------------
template<bool GELU, bool RESID>
__global__ __launch_bounds__(256) void gemm_kernel(const float* __restrict__ A,
                                                   const float* __restrict__ W,
                                                   const float* __restrict__ bias,
                                                   const float* __restrict__ resid,
                                                   float* __restrict__ C,
                                                   int M, int N, int K) {
    __shared__ float As[16][65];  // As[k][row]
    __shared__ float Ws[16][68];  // Ws[k][col]

    int tid = threadIdx.x;
    int tx = tid & 15;        // col group
    int ty = tid >> 4;        // row group
    int row0 = blockIdx.y * 64;
    int col0 = blockIdx.x * 64;

    float acc[4][4] = {};

    for (int k0 = 0; k0 < K; k0 += 16) {
        {
            int r  = tid >> 2;
            int kq = (tid & 3) * 4;
            float4 a = *(const float4*)&A[(size_t)(row0 + r) * K + k0 + kq];
            As[kq + 0][r] = a.x;
            As[kq + 1][r] = a.y;
            As[kq + 2][r] = a.z;
            As[kq + 3][r] = a.w;
        }
        {
            int kr = tid >> 4;
            int cq = (tid & 15) * 4;
            float4 w = *(const float4*)&W[(size_t)(k0 + kr) * N + col0 + cq];
            *(float4*)&Ws[kr][cq] = w;
        }
        __syncthreads();

        #pragma unroll
        for (int k = 0; k < 16; ++k) {
            float a[4], w[4];
            #pragma unroll
            for (int i = 0; i < 4; ++i) a[i] = As[k][ty * 4 + i];
            #pragma unroll
            for (int j = 0; j < 4; ++j) w[j] = Ws[k][tx * 4 + j];
            #pragma unroll
            for (int i = 0; i < 4; ++i)
                #pragma unroll
                for (int j = 0; j < 4; ++j)
                    acc[i][j] += a[i] * w[j];
        }
        __syncthreads();
    }

    float4 bi = *(const float4*)&bias[col0 + tx * 4];
    #pragma unroll
    for (int i = 0; i < 4; ++i) {
        int row = row0 + ty * 4 + i;
        size_t base = (size_t)row * N + col0 + tx * 4;
        float v[4] = {acc[i][0] + bi.x, acc[i][1] + bi.y,
                      acc[i][2] + bi.z, acc[i][3] + bi.w};
        if (RESID) {
            float4 r = *(const float4*)&resid[base];
            v[0] += r.x; v[1] += r.y; v[2] += r.z; v[3] += r.w;
        }
        if (GELU) {
            #pragma unroll
            for (int j = 0; j < 4; ++j)
                v[j] = 0.5f * v[j] * (1.0f + erff(v[j] * 0.70710678118654752f));
        }
        float4 o = {v[0], v[1], v[2], v[3]};
        *(float4*)&C[base] = o;
    }
}

// ---------------------------------------------------------------------------
// Flash-style attention. One block = 64 query rows of one (b,h).
// Iterates 32 K/V tiles of 64 keys; K transposed in LDS (pad 65, GEMM-style),
// V natural (pad 68), P tile in LDS (pad 67). Online softmax; O in registers.
// qkv layout: [b*N+n][3*512] with q at +0, k at +512, v at +1024 (+h*64).
// ---------------------------------------------------------------------------
__global__ __launch_bounds__(256) void fattn_kernel(const float* __restrict__ qkv,
                                                    float* __restrict__ out) {
    __shared__ float Qs[64][65];   // [k][qrow], pre-scaled by 1/8
    __shared__ float Kts[64][65];  // [k][keycol]
    __shared__ float Vs[64][68];   // [keyrow][d]
    __shared__ float Ss[64][67];   // [qrow][keycol] -> P after softmax
    __shared__ float mrun[64], lrun[64], srow[64];

    int tid = threadIdx.x;
    int tx = tid & 15;   // key-col group (S) / d group (PV)
    int ty = tid >> 4;   // q-row group
    int qt = blockIdx.x; // query tile 0..31
    int bh = blockIdx.y; // 0..31
    int b = bh >> 3, h = bh & 7;
    int n0 = qt * 64;
    const size_t base = (size_t)b * N_ * 1536 + (size_t)h * 64;

    // stage Q transposed + pre-scaled (once per block)
    for (int t = tid; t < 1024; t += 256) {
        int r = t >> 4, d4 = (t & 15) * 4;
        float4 q4 = *(const float4*)&qkv[base + (size_t)(n0 + r) * 1536 + d4];
        Qs[d4 + 0][r] = q4.x * 0.125f;
        Qs[d4 + 1][r] = q4.y * 0.125f;
        Qs[d4 + 2][r] = q4.z * 0.125f;
        Qs[d4 + 3][r] = q4.w * 0.125f;
    }
    if (tid < 64) { mrun[tid] = -3.402823466e+38f; lrun[tid] = 0.0f; }
    float o[4][4] = {};
    __syncthreads();

    for (int kt = 0; kt < 32; ++kt) {
        // stage K (transposed) and V tiles
        for (int t = tid; t < 1024; t += 256) {
            int r = t >> 4, d4 = (t & 15) * 4;
            size_t rowoff = base + (size_t)(kt * 64 + r) * 1536;
            float4 k4 = *(const float4*)&qkv[rowoff + 512 + d4];
            Kts[d4 + 0][r] = k4.x;
            Kts[d4 + 1][r] = k4.y;
            Kts[d4 + 2][r] = k4.z;
            Kts[d4 + 3][r] = k4.w;
            float4 v4 = *(const float4*)&qkv[rowoff + 1024 + d4];
            *(float4*)&Vs[r][d4] = v4;
        }
        __syncthreads();

        // S tile: s[i][j] = sum_k Qs[k][4ty+i] * Kts[k][4tx+j]
        float s[4][4] = {};
        #pragma unroll 4
        for (int k = 0; k < 64; ++k) {
            float a[4], w[4];
            #pragma unroll
            for (int i = 0; i < 4; ++i) a[i] = Qs[k][ty * 4 + i];
            #pragma unroll
            for (int j = 0; j < 4; ++j) w[j] = Kts[k][tx * 4 + j];
            #pragma unroll
            for (int i = 0; i < 4; ++i)
                #pragma unroll
                for (int j = 0; j < 4; ++j)
                    s[i][j] += a[i] * w[j];
        }
        #pragma unroll
        for (int i = 0; i < 4; ++i)
            #pragma unroll
            for (int j = 0; j < 4; ++j)
                Ss[ty * 4 + i][tx * 4 + j] = s[i][j];
        __syncthreads();

        // online softmax: row r = tid>>2, quarter q = tid&3 (16 entries each)
        {
            int r = tid >> 2, q = tid & 3;
            float tmax = -3.402823466e+38f;
            #pragma unroll
            for (int j = 0; j < 16; ++j) tmax = fmaxf(tmax, Ss[r][q * 16 + j]);
            tmax = fmaxf(tmax, __shfl_xor(tmax, 1, 64));
            tmax = fmaxf(tmax, __shfl_xor(tmax, 2, 64));
            float mold = mrun[r];
            float mnew = fmaxf(mold, tmax);
            float scl  = __expf(mold - mnew);
            float ps = 0.0f;
            #pragma unroll
            for (int j = 0; j < 16; ++j) {
                float p = __expf(Ss[r][q * 16 + j] - mnew);
                Ss[r][q * 16 + j] = p;
                ps += p;
            }
            ps += __shfl_xor(ps, 1, 64);
            ps += __shfl_xor(ps, 2, 64);
            if (q == 0) {
                lrun[r] = lrun[r] * scl + ps;
                mrun[r] = mnew;
                srow[r] = scl;
            }
        }
        __syncthreads();

        // O = O*scale + P @ V
        {
            float scl[4];
            #pragma unroll
            for (int i = 0; i < 4; ++i) scl[i] = srow[ty * 4 + i];
            #pragma unroll
            for (int i = 0; i < 4; ++i)
                #pragma unroll
                for (int j = 0; j < 4; ++j)
                    o[i][j] *= scl[i];
            #pragma unroll 4
            for (int m = 0; m < 64; ++m) {
                float p[4], v[4];
                #pragma unroll
                for (int i = 0; i < 4; ++i) p[i] = Ss[ty * 4 + i][m];
                #pragma unroll
                for (int j = 0; j < 4; ++j) v[j] = Vs[m][tx * 4 + j];
                #pragma unroll
                for (int i = 0; i < 4; ++i)
                    #pragma unroll
                    for (int j = 0; j < 4; ++j)
                        o[i][j] += p[i] * v[j];
            }
        }
        __syncthreads();  // protect Kts/Vs/Ss before next tile's staging
    }

    // final 1/l normalization + write
    #pragma unroll
    for (int i = 0; i < 4; ++i) {
        float linv = 1.0f / lrun[ty * 4 + i];
        size_t obase = (size_t)(b * N_ + n0 + ty * 4 + i) * D_ + h * 64 + tx * 4;
        #pragma unroll
        for (int j = 0; j < 4; ++j)
            out[obase + j] = o[i][j] * linv;
    }
}

// ---------------------------------------------------------------------------
extern "C" void kernel_launch(void* const* d_in, const int* in_sizes, int n_in,
                              void* d_out, int out_size, void* d_ws, size_t ws_size,
                              hipStream_t stream) {
    const float* x      = (const float*)d_in[0];
    const float* ln1_g  = (const float*)d_in[1];
    const float* ln1_b  = (const float*)d_in[2];
    const float* Wqkv   = (const float*)d_in[3];
    const float* bqkv   = (const float*)d_in[4];
    const float* Wproj  = (const float*)d_in[5];
    const float* bproj  = (const float*)d_in[6];
    const float* ln2_g  = (const float*)d_in[7];
    const float* ln2_b  = (const float*)d_in[8];
    const float* W1     = (const float*)d_in[9];
    const float* b1     = (const float*)d_in[10];
    const float* W2     = (const float*)d_in[11];
    const float* b2     = (const float*)d_in[12];
    float* out = (float*)d_out;

    float* ws = (float*)d_ws;
    float* h       = ws + 0;            // 8192*512
    float* qkv     = ws + 4194304;      // 8192*1536
    float* attnout = ws + 0;            // reuse h
    float* x2      = ws + 16777216;     // 8192*512
    float* h2      = ws + 0;            // reuse
    float* ffh     = ws + 20971520;     // 8192*2048

    dim3 blk(256);

    // 1. h = LN1(x)
    ln_kernel<<<ROWS_ / 4, blk, 0, stream>>>(x, ln1_g, ln1_b, h);

    // 2. qkv = h @ Wqkv + bqkv
    gemm_kernel<false, false><<<dim3(1536 / 64, ROWS_ / 64), blk, 0, stream>>>(
        h, Wqkv, bqkv, nullptr, qkv, ROWS_, 1536, 512);

    // 3. attnout = softmax(qk^T)v   (flash-style)
    fattn_kernel<<<dim3(N_ / 64, B_ * H_), blk, 0, stream>>>(qkv, attnout);

    // 4. x2 = x + attnout @ Wproj + bproj
    gemm_kernel<false, true><<<dim3(512 / 64, ROWS_ / 64), blk, 0, stream>>>(
        attnout, Wproj, bproj, x, x2, ROWS_, 512, 512);

    // 5. h2 = LN2(x2)
    ln_kernel<<<ROWS_ / 4, blk, 0, stream>>>(x2, ln2_g, ln2_b, h2);

    // 6. ffh = gelu(h2 @ W1 + b1)
    gemm_kernel<true, false><<<dim3(2048 / 64, ROWS_ / 64), blk, 0, stream>>>(
        h2, W1, b1, nullptr, ffh, ROWS_, 2048, 512);

    // 7. out = x2 + ffh @ W2 + b2
    gemm_kernel<false, true><<<dim3(512 / 64, ROWS_ / 64), blk, 0, stream>>>(
        ffh, W2, b2, x2, out, ROWS_, 512, 2048);
}

// Round 3
// 279.155 us; speedup vs baseline: 22.2650x; 4.9633x over previous
//
#include <hip/hip_runtime.h>

#define B_ 4
#define N_ 2048
#define D_ 512
#define H_ 8
#define DH_ 64
#define ROWS_ 8192

typedef float f32x4 __attribute__((ext_vector_type(4)));
typedef short short8v __attribute__((ext_vector_type(8)));
typedef short short4v __attribute__((ext_vector_type(4)));

__device__ __forceinline__ short f2bf(float f) {
    unsigned u = __builtin_bit_cast(unsigned, f);
    u += 0x7FFFu + ((u >> 16) & 1u);   // round-to-nearest-even
    return (short)(u >> 16);
}

// ---------------------------------------------------------------------------
// LayerNorm fp32-in -> bf16-out. One wave per row of 512; 4 rows/block.
// ---------------------------------------------------------------------------
__global__ __launch_bounds__(256) void ln_bf16_kernel(const float* __restrict__ x,
                                                      const float* __restrict__ g,
                                                      const float* __restrict__ bb,
                                                      short* __restrict__ out) {
    int wave = threadIdx.x >> 6;
    int lane = threadIdx.x & 63;
    int row  = blockIdx.x * 4 + wave;
    const float* xr = x + (size_t)row * D_;

    float4 v0 = ((const float4*)xr)[lane * 2 + 0];
    float4 v1 = ((const float4*)xr)[lane * 2 + 1];

    float s = v0.x + v0.y + v0.z + v0.w + v1.x + v1.y + v1.z + v1.w;
    #pragma unroll
    for (int off = 32; off; off >>= 1) s += __shfl_xor(s, off, 64);
    float mu = s * (1.0f / D_);

    float d0 = v0.x - mu, d1 = v0.y - mu, d2 = v0.z - mu, d3 = v0.w - mu;
    float d4 = v1.x - mu, d5 = v1.y - mu, d6 = v1.z - mu, d7 = v1.w - mu;
    float vs = d0*d0 + d1*d1 + d2*d2 + d3*d3 + d4*d4 + d5*d5 + d6*d6 + d7*d7;
    #pragma unroll
    for (int off = 32; off; off >>= 1) vs += __shfl_xor(vs, off, 64);
    float rstd = rsqrtf(vs * (1.0f / D_) + 1e-5f);

    float4 g0 = ((const float4*)g)[lane * 2 + 0];
    float4 g1 = ((const float4*)g)[lane * 2 + 1];
    float4 b0 = ((const float4*)bb)[lane * 2 + 0];
    float4 b1 = ((const float4*)bb)[lane * 2 + 1];

    short8v ov;
    ov[0] = f2bf(d0 * rstd * g0.x + b0.x);
    ov[1] = f2bf(d1 * rstd * g0.y + b0.y);
    ov[2] = f2bf(d2 * rstd * g0.z + b0.z);
    ov[3] = f2bf(d3 * rstd * g0.w + b0.w);
    ov[4] = f2bf(d4 * rstd * g1.x + b1.x);
    ov[5] = f2bf(d5 * rstd * g1.y + b1.y);
    ov[6] = f2bf(d6 * rstd * g1.z + b1.z);
    ov[7] = f2bf(d7 * rstd * g1.w + b1.w);
    *(short8v*)&out[(size_t)row * D_ + lane * 8] = ov;
}

// ---------------------------------------------------------------------------
// Weight transpose + cvt: W[K][N] fp32 -> WT[N][K] bf16. 64x64 tile per block.
// ---------------------------------------------------------------------------
__global__ __launch_bounds__(256) void wt_kernel(const float* __restrict__ W,
                                                 short* __restrict__ WT,
                                                 int K, int N) {
    __shared__ short Ts[64][72];
    int tid = threadIdx.x;
    int n0 = blockIdx.x * 64, k0 = blockIdx.y * 64;

    #pragma unroll
    for (int i = 0; i < 4; ++i) {
        int idx = tid + i * 256;            // 1024 float4 chunks
        int k = idx >> 4, nq = (idx & 15) * 4;
        float4 wv = *(const float4*)&W[(size_t)(k0 + k) * N + n0 + nq];
        short4v t;
        t[0] = f2bf(wv.x); t[1] = f2bf(wv.y); t[2] = f2bf(wv.z); t[3] = f2bf(wv.w);
        *(short4v*)&Ts[k][nq] = t;
    }
    __syncthreads();

    int n = tid >> 2, kq = (tid & 3) * 16;
    short8v o0, o1;
    #pragma unroll
    for (int j = 0; j < 8; ++j) { o0[j] = Ts[kq + j][n]; o1[j] = Ts[kq + 8 + j][n]; }
    *(short8v*)&WT[(size_t)(n0 + n) * K + k0 + kq]     = o0;
    *(short8v*)&WT[(size_t)(n0 + n) * K + k0 + kq + 8] = o1;
}

// ---------------------------------------------------------------------------
// V transpose per head: qkv_bf[row][1536] (v at +1024) -> vtg[bh][64 d][2048 n]
// ---------------------------------------------------------------------------
__global__ __launch_bounds__(256) void vt_kernel(const short* __restrict__ qkvb,
                                                 short* __restrict__ vtg) {
    __shared__ short Ts[64][72];
    int tid = threadIdx.x;
    int n0 = blockIdx.x * 64;
    int bh = blockIdx.y;
    int b = bh >> 3, h = bh & 7;

    #pragma unroll
    for (int i = 0; i < 2; ++i) {
        int idx = tid + i * 256;            // 512 chunks of 8 bf16
        int n = idx >> 3, dq = (idx & 7) * 8;
        *(short8v*)&Ts[n][dq] =
            *(const short8v*)&qkvb[(size_t)(b * N_ + n0 + n) * 1536 + 1024 + h * 64 + dq];
    }
    __syncthreads();

    int d = tid >> 2, nq = (tid & 3) * 16;
    short8v o0, o1;
    #pragma unroll
    for (int j = 0; j < 8; ++j) { o0[j] = Ts[nq + j][d]; o1[j] = Ts[nq + 8 + j][d]; }
    size_t base = ((size_t)bh * 64 + d) * N_ + n0 + nq;
    *(short8v*)&vtg[base]     = o0;
    *(short8v*)&vtg[base + 8] = o1;
}

// ---------------------------------------------------------------------------
// bf16 MFMA GEMM: C[M,N] = A[M,K] @ BT[N,K]^T + bias (+resid)(+gelu)
// 128x128 tile, BK=64, 256 thr = 4 waves (2x2), each wave 64x64 = 4x4 frags.
// ---------------------------------------------------------------------------
template<bool GELU, bool RESID, bool OUTBF>
__global__ __launch_bounds__(256) void gemm_bf16(const short* __restrict__ A,
                                                 const short* __restrict__ BT,
                                                 const float* __restrict__ bias,
                                                 const float* __restrict__ resid,
                                                 float* __restrict__ Cf,
                                                 short* __restrict__ Cb,
                                                 int M, int N, int K) {
    __shared__ short As[128][72];
    __shared__ short Bs[128][72];
    int tid = threadIdx.x;
    int l = tid & 63, w = tid >> 6;
    int wr = w >> 1, wc = w & 1;
    int l15 = l & 15, lg = l >> 4;
    int row0 = blockIdx.y * 128, col0 = blockIdx.x * 128;

    const f32x4 zero4 = {0.f, 0.f, 0.f, 0.f};
    f32x4 acc[4][4];
    #pragma unroll
    for (int m = 0; m < 4; ++m)
        #pragma unroll
        for (int n = 0; n < 4; ++n) acc[m][n] = zero4;

    for (int k0 = 0; k0 < K; k0 += 64) {
        #pragma unroll
        for (int i = 0; i < 4; ++i) {
            int chunk = tid + i * 256;       // 1024 chunks of 8 bf16 per matrix
            int r = chunk >> 3, kq = (chunk & 7) * 8;
            *(short8v*)&As[r][kq] = *(const short8v*)&A[(size_t)(row0 + r) * K + k0 + kq];
            *(short8v*)&Bs[r][kq] = *(const short8v*)&BT[(size_t)(col0 + r) * K + k0 + kq];
        }
        __syncthreads();

        #pragma unroll
        for (int ks = 0; ks < 2; ++ks) {
            short8v a[4], b[4];
            #pragma unroll
            for (int m = 0; m < 4; ++m)
                a[m] = *(const short8v*)&As[wr * 64 + m * 16 + l15][ks * 32 + lg * 8];
            #pragma unroll
            for (int n = 0; n < 4; ++n)
                b[n] = *(const short8v*)&Bs[wc * 64 + n * 16 + l15][ks * 32 + lg * 8];
            #pragma unroll
            for (int m = 0; m < 4; ++m)
                #pragma unroll
                for (int n = 0; n < 4; ++n)
                    acc[m][n] = __builtin_amdgcn_mfma_f32_16x16x32_bf16(a[m], b[n], acc[m][n], 0, 0, 0);
        }
        __syncthreads();
    }

    #pragma unroll
    for (int n = 0; n < 4; ++n) {
        int col = col0 + wc * 64 + n * 16 + l15;
        float bv = bias[col];
        #pragma unroll
        for (int m = 0; m < 4; ++m) {
            #pragma unroll
            for (int i = 0; i < 4; ++i) {
                int row = row0 + wr * 64 + m * 16 + lg * 4 + i;
                size_t off = (size_t)row * N + col;
                float v = acc[m][n][i] + bv;
                if (RESID) v += resid[off];
                if (GELU)  v = 0.5f * v * (1.0f + erff(v * 0.70710678118654752f));
                if (OUTBF) Cb[off] = f2bf(v);
                else       Cf[off] = v;
            }
        }
    }
}

// ---------------------------------------------------------------------------
// Flash attention, bf16 MFMA. Block = 64 q-rows of one (b,h); 4 waves x 16 q.
// S = Q K^T via MFMA (scale folded post-MFMA), fp32 online softmax in regs,
// P through LDS (re-fragment), O += P V via MFMA with V^T tiles from vtg.
// ---------------------------------------------------------------------------
__global__ __launch_bounds__(256) void fattn_bf16(const short* __restrict__ qkvb,
                                                  const short* __restrict__ vtg,
                                                  short* __restrict__ attnout) {
    __shared__ short Qs[64][72], Ks[64][72], Vt[64][72], Ps[64][72];
    int tid = threadIdx.x;
    int l = tid & 63, w = tid >> 6;
    int l15 = l & 15, lg = l >> 4;
    int qt = blockIdx.x, bh = blockIdx.y;
    int b = bh >> 3, h = bh & 7;
    int n0 = qt * 64;
    int qb = w * 16;

    #pragma unroll
    for (int i = 0; i < 2; ++i) {
        int chunk = tid + i * 256;
        int r = chunk >> 3, cq = (chunk & 7) * 8;
        *(short8v*)&Qs[r][cq] =
            *(const short8v*)&qkvb[(size_t)(b * N_ + n0 + r) * 1536 + h * 64 + cq];
    }

    const f32x4 zero4 = {0.f, 0.f, 0.f, 0.f};
    f32x4 o[4];
    float m_run[4], l_run[4];
    #pragma unroll
    for (int i = 0; i < 4; ++i) { o[i] = zero4; m_run[i] = -3.402823466e+38f; l_run[i] = 0.f; }

    for (int kt = 0; kt < 32; ++kt) {
        #pragma unroll
        for (int i = 0; i < 2; ++i) {
            int chunk = tid + i * 256;
            int r = chunk >> 3, cq = (chunk & 7) * 8;
            *(short8v*)&Ks[r][cq] =
                *(const short8v*)&qkvb[(size_t)(b * N_ + kt * 64 + r) * 1536 + 512 + h * 64 + cq];
            *(short8v*)&Vt[r][cq] =
                *(const short8v*)&vtg[((size_t)bh * 64 + r) * N_ + kt * 64 + cq];
        }
        __syncthreads();

        // S tile: 16q x 64keys per wave
        f32x4 s[4];
        short8v aQ0 = *(const short8v*)&Qs[qb + l15][lg * 8];
        short8v aQ1 = *(const short8v*)&Qs[qb + l15][32 + lg * 8];
        #pragma unroll
        for (int kf = 0; kf < 4; ++kf) {
            short8v k0v = *(const short8v*)&Ks[kf * 16 + l15][lg * 8];
            short8v k1v = *(const short8v*)&Ks[kf * 16 + l15][32 + lg * 8];
            s[kf] = __builtin_amdgcn_mfma_f32_16x16x32_bf16(aQ0, k0v, zero4, 0, 0, 0);
            s[kf] = __builtin_amdgcn_mfma_f32_16x16x32_bf16(aQ1, k1v, s[kf], 0, 0, 0);
            s[kf] *= 0.125f;   // 1/sqrt(64)
        }

        // online softmax; lane holds rows q = qb + lg*4 + i, col = kf*16 + l15
        #pragma unroll
        for (int i = 0; i < 4; ++i) {
            float mx = fmaxf(fmaxf(s[0][i], s[1][i]), fmaxf(s[2][i], s[3][i]));
            #pragma unroll
            for (int off = 1; off < 16; off <<= 1)
                mx = fmaxf(mx, __shfl_xor(mx, off, 64));
            float mnew = fmaxf(m_run[i], mx);
            float scl = __expf(m_run[i] - mnew);
            m_run[i] = mnew;
            float ps = 0.f;
            #pragma unroll
            for (int kf = 0; kf < 4; ++kf) {
                float pv = __expf(s[kf][i] - mnew);
                s[kf][i] = pv;
                ps += pv;
            }
            #pragma unroll
            for (int off = 1; off < 16; off <<= 1)
                ps += __shfl_xor(ps, off, 64);
            l_run[i] = l_run[i] * scl + ps;
            #pragma unroll
            for (int df = 0; df < 4; ++df) o[df][i] *= scl;
        }

        // P -> LDS (re-fragment for PV A-operand)
        #pragma unroll
        for (int kf = 0; kf < 4; ++kf)
            #pragma unroll
            for (int i = 0; i < 4; ++i)
                Ps[qb + lg * 4 + i][kf * 16 + l15] = f2bf(s[kf][i]);
        __syncthreads();

        // O += P V
        short8v aP0 = *(const short8v*)&Ps[qb + l15][lg * 8];
        short8v aP1 = *(const short8v*)&Ps[qb + l15][32 + lg * 8];
        #pragma unroll
        for (int df = 0; df < 4; ++df) {
            short8v v0 = *(const short8v*)&Vt[df * 16 + l15][lg * 8];
            short8v v1 = *(const short8v*)&Vt[df * 16 + l15][32 + lg * 8];
            o[df] = __builtin_amdgcn_mfma_f32_16x16x32_bf16(aP0, v0, o[df], 0, 0, 0);
            o[df] = __builtin_amdgcn_mfma_f32_16x16x32_bf16(aP1, v1, o[df], 0, 0, 0);
        }
        __syncthreads();
    }

    #pragma unroll
    for (int df = 0; df < 4; ++df)
        #pragma unroll
        for (int i = 0; i < 4; ++i) {
            float v = o[df][i] / l_run[i];
            attnout[(size_t)(b * N_ + n0 + qb + lg * 4 + i) * D_ + h * 64 + df * 16 + l15] = f2bf(v);
        }
}

// ---------------------------------------------------------------------------
extern "C" void kernel_launch(void* const* d_in, const int* in_sizes, int n_in,
                              void* d_out, int out_size, void* d_ws, size_t ws_size,
                              hipStream_t stream) {
    const float* x      = (const float*)d_in[0];
    const float* ln1_g  = (const float*)d_in[1];
    const float* ln1_b  = (const float*)d_in[2];
    const float* Wqkv   = (const float*)d_in[3];
    const float* bqkv   = (const float*)d_in[4];
    const float* Wproj  = (const float*)d_in[5];
    const float* bproj  = (const float*)d_in[6];
    const float* ln2_g  = (const float*)d_in[7];
    const float* ln2_b  = (const float*)d_in[8];
    const float* W1     = (const float*)d_in[9];
    const float* b1     = (const float*)d_in[10];
    const float* W2     = (const float*)d_in[11];
    const float* b2     = (const float*)d_in[12];
    float* out = (float*)d_out;

    char* ws = (char*)d_ws;
    short* h_bf    = (short*)(ws + (size_t)0);
    short* qkv_bf  = (short*)(ws + ((size_t)8  << 20));
    short* vtg     = (short*)(ws + ((size_t)32 << 20));
    short* attn_bf = (short*)(ws + ((size_t)40 << 20));
    float* x2      = (float*)(ws + ((size_t)48 << 20));
    short* h2_bf   = (short*)(ws + ((size_t)64 << 20));
    short* ffh_bf  = (short*)(ws + ((size_t)72 << 20));
    short* WTqkv   = (short*)(ws + ((size_t)104 << 20));
    short* WTproj  = (short*)(ws + ((size_t)106 << 20));
    short* WT1     = (short*)(ws + ((size_t)108 << 20));
    short* WT2     = (short*)(ws + ((size_t)110 << 20));

    dim3 blk(256);

    // weight transposes (bf16)
    wt_kernel<<<dim3(24, 8),  blk, 0, stream>>>(Wqkv,  WTqkv,  512,  1536);
    wt_kernel<<<dim3(8, 8),   blk, 0, stream>>>(Wproj, WTproj, 512,  512);
    wt_kernel<<<dim3(32, 8),  blk, 0, stream>>>(W1,    WT1,    512,  2048);
    wt_kernel<<<dim3(8, 32),  blk, 0, stream>>>(W2,    WT2,    2048, 512);

    // 1. h = LN1(x)  (bf16)
    ln_bf16_kernel<<<ROWS_ / 4, blk, 0, stream>>>(x, ln1_g, ln1_b, h_bf);

    // 2. qkv = h @ Wqkv + bqkv  (bf16 out)
    gemm_bf16<false, false, true><<<dim3(12, 64), blk, 0, stream>>>(
        h_bf, WTqkv, bqkv, nullptr, nullptr, qkv_bf, ROWS_, 1536, 512);

    // 3a. V transpose per head
    vt_kernel<<<dim3(32, 32), blk, 0, stream>>>(qkv_bf, vtg);

    // 3b. attention (bf16 out)
    fattn_bf16<<<dim3(32, 32), blk, 0, stream>>>(qkv_bf, vtg, attn_bf);

    // 4. x2 = x + attn @ Wproj + bproj  (fp32 out)
    gemm_bf16<false, true, false><<<dim3(4, 64), blk, 0, stream>>>(
        attn_bf, WTproj, bproj, x, x2, nullptr, ROWS_, 512, 512);

    // 5. h2 = LN2(x2)  (bf16)
    ln_bf16_kernel<<<ROWS_ / 4, blk, 0, stream>>>(x2, ln2_g, ln2_b, h2_bf);

    // 6. ffh = gelu(h2 @ W1 + b1)  (bf16 out)
    gemm_bf16<true, false, true><<<dim3(16, 64), blk, 0, stream>>>(
        h2_bf, WT1, b1, nullptr, nullptr, ffh_bf, ROWS_, 2048, 512);

    // 7. out = x2 + ffh @ W2 + b2  (fp32 out)
    gemm_bf16<false, true, false><<<dim3(4, 64), blk, 0, stream>>>(
        ffh_bf, WT2, b2, x2, out, nullptr, ROWS_, 512, 2048);
}

// Round 4
// 235.363 us; speedup vs baseline: 26.4077x; 1.1861x over previous
//
#include <hip/hip_runtime.h>

#define B_ 4
#define N_ 2048
#define D_ 512
#define H_ 8
#define DH_ 64
#define ROWS_ 8192

typedef float f32x4 __attribute__((ext_vector_type(4)));
typedef short short8v __attribute__((ext_vector_type(8)));
typedef short short4v __attribute__((ext_vector_type(4)));

__device__ __forceinline__ short f2bf(float f) {
    unsigned u = __builtin_bit_cast(unsigned, f);
    u += 0x7FFFu + ((u >> 16) & 1u);   // round-to-nearest-even
    return (short)(u >> 16);
}

__device__ __forceinline__ unsigned cvtpk_bf16(float lo, float hi) {
    unsigned r;
    asm("v_cvt_pk_bf16_f32 %0, %1, %2" : "=v"(r) : "v"(lo), "v"(hi));
    return r;
}

// ---------------------------------------------------------------------------
// LayerNorm fp32-in -> bf16-out. One wave per row of 512; 4 rows/block.
// ---------------------------------------------------------------------------
__global__ __launch_bounds__(256) void ln_bf16_kernel(const float* __restrict__ x,
                                                      const float* __restrict__ g,
                                                      const float* __restrict__ bb,
                                                      short* __restrict__ out) {
    int wave = threadIdx.x >> 6;
    int lane = threadIdx.x & 63;
    int row  = blockIdx.x * 4 + wave;
    const float* xr = x + (size_t)row * D_;

    float4 v0 = ((const float4*)xr)[lane * 2 + 0];
    float4 v1 = ((const float4*)xr)[lane * 2 + 1];

    float s = v0.x + v0.y + v0.z + v0.w + v1.x + v1.y + v1.z + v1.w;
    #pragma unroll
    for (int off = 32; off; off >>= 1) s += __shfl_xor(s, off, 64);
    float mu = s * (1.0f / D_);

    float d0 = v0.x - mu, d1 = v0.y - mu, d2 = v0.z - mu, d3 = v0.w - mu;
    float d4 = v1.x - mu, d5 = v1.y - mu, d6 = v1.z - mu, d7 = v1.w - mu;
    float vs = d0*d0 + d1*d1 + d2*d2 + d3*d3 + d4*d4 + d5*d5 + d6*d6 + d7*d7;
    #pragma unroll
    for (int off = 32; off; off >>= 1) vs += __shfl_xor(vs, off, 64);
    float rstd = rsqrtf(vs * (1.0f / D_) + 1e-5f);

    float4 g0 = ((const float4*)g)[lane * 2 + 0];
    float4 g1 = ((const float4*)g)[lane * 2 + 1];
    float4 b0 = ((const float4*)bb)[lane * 2 + 0];
    float4 b1 = ((const float4*)bb)[lane * 2 + 1];

    short8v ov;
    ov[0] = f2bf(d0 * rstd * g0.x + b0.x);
    ov[1] = f2bf(d1 * rstd * g0.y + b0.y);
    ov[2] = f2bf(d2 * rstd * g0.z + b0.z);
    ov[3] = f2bf(d3 * rstd * g0.w + b0.w);
    ov[4] = f2bf(d4 * rstd * g1.x + b1.x);
    ov[5] = f2bf(d5 * rstd * g1.y + b1.y);
    ov[6] = f2bf(d6 * rstd * g1.z + b1.z);
    ov[7] = f2bf(d7 * rstd * g1.w + b1.w);
    *(short8v*)&out[(size_t)row * D_ + lane * 8] = ov;
}

// ---------------------------------------------------------------------------
// Weight transpose + cvt: W[K][N] fp32 -> WT[N][K] bf16. 64x64 tile per block.
// ---------------------------------------------------------------------------
__global__ __launch_bounds__(256) void wt_kernel(const float* __restrict__ W,
                                                 short* __restrict__ WT,
                                                 int K, int N) {
    __shared__ short Ts[64][72];
    int tid = threadIdx.x;
    int n0 = blockIdx.x * 64, k0 = blockIdx.y * 64;

    #pragma unroll
    for (int i = 0; i < 4; ++i) {
        int idx = tid + i * 256;            // 1024 float4 chunks
        int k = idx >> 4, nq = (idx & 15) * 4;
        float4 wv = *(const float4*)&W[(size_t)(k0 + k) * N + n0 + nq];
        short4v t;
        t[0] = f2bf(wv.x); t[1] = f2bf(wv.y); t[2] = f2bf(wv.z); t[3] = f2bf(wv.w);
        *(short4v*)&Ts[k][nq] = t;
    }
    __syncthreads();

    int n = tid >> 2, kq = (tid & 3) * 16;
    short8v o0, o1;
    #pragma unroll
    for (int j = 0; j < 8; ++j) { o0[j] = Ts[kq + j][n]; o1[j] = Ts[kq + 8 + j][n]; }
    *(short8v*)&WT[(size_t)(n0 + n) * K + k0 + kq]     = o0;
    *(short8v*)&WT[(size_t)(n0 + n) * K + k0 + kq + 8] = o1;
}

// ---------------------------------------------------------------------------
// V transpose per head: qkv_bf[row][1536] (v at +1024) -> vtg[bh][64 d][2048 n]
// ---------------------------------------------------------------------------
__global__ __launch_bounds__(256) void vt_kernel(const short* __restrict__ qkvb,
                                                 short* __restrict__ vtg) {
    __shared__ short Ts[64][72];
    int tid = threadIdx.x;
    int n0 = blockIdx.x * 64;
    int bh = blockIdx.y;
    int b = bh >> 3, h = bh & 7;

    #pragma unroll
    for (int i = 0; i < 2; ++i) {
        int idx = tid + i * 256;            // 512 chunks of 8 bf16
        int n = idx >> 3, dq = (idx & 7) * 8;
        *(short8v*)&Ts[n][dq] =
            *(const short8v*)&qkvb[(size_t)(b * N_ + n0 + n) * 1536 + 1024 + h * 64 + dq];
    }
    __syncthreads();

    int d = tid >> 2, nq = (tid & 3) * 16;
    short8v o0, o1;
    #pragma unroll
    for (int j = 0; j < 8; ++j) { o0[j] = Ts[nq + j][d]; o1[j] = Ts[nq + 8 + j][d]; }
    size_t base = ((size_t)bh * 64 + d) * N_ + n0 + nq;
    *(short8v*)&vtg[base]     = o0;
    *(short8v*)&vtg[base + 8] = o1;
}

// ---------------------------------------------------------------------------
// bf16 MFMA GEMM: C[M,N] = A[M,K] @ BT[N,K]^T + bias (+resid)(+gelu)
// 128x128 tile, BK=64, 256 thr = 4 waves (2x2), each wave 64x64 = 4x4 frags.
// ---------------------------------------------------------------------------
template<bool GELU, bool RESID, bool OUTBF>
__global__ __launch_bounds__(256) void gemm_bf16(const short* __restrict__ A,
                                                 const short* __restrict__ BT,
                                                 const float* __restrict__ bias,
                                                 const float* __restrict__ resid,
                                                 float* __restrict__ Cf,
                                                 short* __restrict__ Cb,
                                                 int M, int N, int K) {
    __shared__ short As[128][72];
    __shared__ short Bs[128][72];
    int tid = threadIdx.x;
    int l = tid & 63, w = tid >> 6;
    int wr = w >> 1, wc = w & 1;
    int l15 = l & 15, lg = l >> 4;
    int row0 = blockIdx.y * 128, col0 = blockIdx.x * 128;

    const f32x4 zero4 = {0.f, 0.f, 0.f, 0.f};
    f32x4 acc[4][4];
    #pragma unroll
    for (int m = 0; m < 4; ++m)
        #pragma unroll
        for (int n = 0; n < 4; ++n) acc[m][n] = zero4;

    for (int k0 = 0; k0 < K; k0 += 64) {
        #pragma unroll
        for (int i = 0; i < 4; ++i) {
            int chunk = tid + i * 256;       // 1024 chunks of 8 bf16 per matrix
            int r = chunk >> 3, kq = (chunk & 7) * 8;
            *(short8v*)&As[r][kq] = *(const short8v*)&A[(size_t)(row0 + r) * K + k0 + kq];
            *(short8v*)&Bs[r][kq] = *(const short8v*)&BT[(size_t)(col0 + r) * K + k0 + kq];
        }
        __syncthreads();

        #pragma unroll
        for (int ks = 0; ks < 2; ++ks) {
            short8v a[4], b[4];
            #pragma unroll
            for (int m = 0; m < 4; ++m)
                a[m] = *(const short8v*)&As[wr * 64 + m * 16 + l15][ks * 32 + lg * 8];
            #pragma unroll
            for (int n = 0; n < 4; ++n)
                b[n] = *(const short8v*)&Bs[wc * 64 + n * 16 + l15][ks * 32 + lg * 8];
            #pragma unroll
            for (int m = 0; m < 4; ++m)
                #pragma unroll
                for (int n = 0; n < 4; ++n)
                    acc[m][n] = __builtin_amdgcn_mfma_f32_16x16x32_bf16(a[m], b[n], acc[m][n], 0, 0, 0);
        }
        __syncthreads();
    }

    #pragma unroll
    for (int n = 0; n < 4; ++n) {
        int col = col0 + wc * 64 + n * 16 + l15;
        float bv = bias[col];
        #pragma unroll
        for (int m = 0; m < 4; ++m) {
            #pragma unroll
            for (int i = 0; i < 4; ++i) {
                int row = row0 + wr * 64 + m * 16 + lg * 4 + i;
                size_t off = (size_t)row * N + col;
                float v = acc[m][n][i] + bv;
                if (RESID) v += resid[off];
                if (GELU)  v = 0.5f * v * (1.0f + erff(v * 0.70710678118654752f));
                if (OUTBF) Cb[off] = f2bf(v);
                else       Cf[off] = v;
            }
        }
    }
}

// ---------------------------------------------------------------------------
// Flash attention, swapped-operand MFMA form.
// Block = 128 q-rows of one (b,h); 4 waves x 32 q-rows (2 q-frags of 16).
// QK^T swapped: S'[key][q] = mfma(K, Q)  -> lane holds 16 keys of q = lane&15
//   => softmax row reduce = in-lane + shfl_xor(16) + shfl_xor(32).
// P packed to bf16 (v_cvt_pk) into wave-private PsT[q][key] rows.
// PV swapped:  O'[d][q]   = mfma(V^T, P) -> same q = lane&15 => scalar m/l.
// K/V double-buffered in LDS with register prefetch; 1 barrier per tile.
// ---------------------------------------------------------------------------
__global__ __launch_bounds__(256) void fattn_bf16(const short* __restrict__ qkvb,
                                                  const short* __restrict__ vtg,
                                                  short* __restrict__ attnout) {
    __shared__ short Ks[2][64][72];
    __shared__ short Vt[2][64][72];
    __shared__ short PsT[128][72];   // [q local][key], wave-private rows

    int tid = threadIdx.x;
    int l = tid & 63, w = tid >> 6;
    int l15 = l & 15, lg = l >> 4;
    int qt = blockIdx.x, bh = blockIdx.y;
    int b = bh >> 3, h = bh & 7;
    int n0 = qt * 128;
    int qb = w * 32;
    const float kScale = 0.18033688011112042f;  // (1/8) * log2(e)

    // Q b-fragments in registers (held for whole kernel)
    short8v bQ[2][2];
    #pragma unroll
    for (int qi = 0; qi < 2; ++qi)
        #pragma unroll
        for (int ks = 0; ks < 2; ++ks)
            bQ[qi][ks] = *(const short8v*)
                &qkvb[(size_t)(b * N_ + n0 + qb + qi * 16 + l15) * 1536 + h * 64 + ks * 32 + lg * 8];

    const f32x4 zero4 = {0.f, 0.f, 0.f, 0.f};
    f32x4 o[2][4];
    float m_run[2], l_run[2];
    #pragma unroll
    for (int qi = 0; qi < 2; ++qi) {
        m_run[qi] = -3.402823466e+38f;
        l_run[qi] = 0.f;
        #pragma unroll
        for (int df = 0; df < 4; ++df) o[qi][df] = zero4;
    }

    // staging geometry: 256 threads x 2 chunks cover a 64x64 bf16 tile
    int sr0 = tid >> 3, scq = (tid & 7) * 8;           // chunk 0
    int sr1 = (tid + 256) >> 3;                        // chunk 1 (same scq)
    short8v kreg[2], vreg[2];

    // prologue: stage tile 0
    {
        const size_t krow0 = (size_t)(b * N_ + sr0) * 1536 + 512 + h * 64 + scq;
        const size_t krow1 = (size_t)(b * N_ + sr1) * 1536 + 512 + h * 64 + scq;
        kreg[0] = *(const short8v*)&qkvb[krow0];
        kreg[1] = *(const short8v*)&qkvb[krow1];
        vreg[0] = *(const short8v*)&vtg[((size_t)bh * 64 + sr0) * N_ + scq];
        vreg[1] = *(const short8v*)&vtg[((size_t)bh * 64 + sr1) * N_ + scq];
        *(short8v*)&Ks[0][sr0][scq] = kreg[0];
        *(short8v*)&Ks[0][sr1][scq] = kreg[1];
        *(short8v*)&Vt[0][sr0][scq] = vreg[0];
        *(short8v*)&Vt[0][sr1][scq] = vreg[1];
    }
    __syncthreads();

    int cur = 0;
    for (int kt = 0; kt < 32; ++kt) {
        // issue next tile's global loads (overlap with compute)
        if (kt < 31) {
            int kn = (kt + 1) * 64;
            kreg[0] = *(const short8v*)&qkvb[(size_t)(b * N_ + kn + sr0) * 1536 + 512 + h * 64 + scq];
            kreg[1] = *(const short8v*)&qkvb[(size_t)(b * N_ + kn + sr1) * 1536 + 512 + h * 64 + scq];
            vreg[0] = *(const short8v*)&vtg[((size_t)bh * 64 + sr0) * N_ + kn + scq];
            vreg[1] = *(const short8v*)&vtg[((size_t)bh * 64 + sr1) * N_ + kn + scq];
        }

        // ---- QK^T (swapped): s[qi][kf] holds S'[key = kf*16+lg*4+i][q = l15]
        f32x4 s[2][4];
        #pragma unroll
        for (int kf = 0; kf < 4; ++kf) {
            short8v aK0 = *(const short8v*)&Ks[cur][kf * 16 + l15][lg * 8];
            short8v aK1 = *(const short8v*)&Ks[cur][kf * 16 + l15][32 + lg * 8];
            #pragma unroll
            for (int qi = 0; qi < 2; ++qi) {
                s[qi][kf] = __builtin_amdgcn_mfma_f32_16x16x32_bf16(aK0, bQ[qi][0], zero4, 0, 0, 0);
                s[qi][kf] = __builtin_amdgcn_mfma_f32_16x16x32_bf16(aK1, bQ[qi][1], s[qi][kf], 0, 0, 0);
            }
        }

        // ---- online softmax (raw-score domain, scale folded into exp2)
        #pragma unroll
        for (int qi = 0; qi < 2; ++qi) {
            float t0 = fmaxf(fmaxf(s[qi][0][0], s[qi][0][1]), fmaxf(s[qi][0][2], s[qi][0][3]));
            float t1 = fmaxf(fmaxf(s[qi][1][0], s[qi][1][1]), fmaxf(s[qi][1][2], s[qi][1][3]));
            float t2 = fmaxf(fmaxf(s[qi][2][0], s[qi][2][1]), fmaxf(s[qi][2][2], s[qi][2][3]));
            float t3 = fmaxf(fmaxf(s[qi][3][0], s[qi][3][1]), fmaxf(s[qi][3][2], s[qi][3][3]));
            float tm = fmaxf(fmaxf(t0, t1), fmaxf(t2, t3));
            tm = fmaxf(tm, __shfl_xor(tm, 16, 64));
            tm = fmaxf(tm, __shfl_xor(tm, 32, 64));
            float mnew = fmaxf(m_run[qi], tm);
            float scl = exp2f((m_run[qi] - mnew) * kScale);
            m_run[qi] = mnew;
            float nmk = -mnew * kScale;
            float ps = 0.f;
            #pragma unroll
            for (int kf = 0; kf < 4; ++kf) {
                #pragma unroll
                for (int i = 0; i < 4; ++i) {
                    float p = exp2f(fmaf(s[qi][kf][i], kScale, nmk));
                    s[qi][kf][i] = p;
                    ps += p;
                }
            }
            ps += __shfl_xor(ps, 16, 64);
            ps += __shfl_xor(ps, 32, 64);
            l_run[qi] = l_run[qi] * scl + ps;
            #pragma unroll
            for (int df = 0; df < 4; ++df) o[qi][df] *= scl;

            // pack P -> PsT[q][key]; keys kf*16+lg*4+{0..3} contiguous
            int qrow = qb + qi * 16 + l15;
            #pragma unroll
            for (int kf = 0; kf < 4; ++kf) {
                uint2 uu;
                uu.x = cvtpk_bf16(s[qi][kf][0], s[qi][kf][1]);
                uu.y = cvtpk_bf16(s[qi][kf][2], s[qi][kf][3]);
                *(uint2*)&PsT[qrow][kf * 16 + lg * 4] = uu;
            }
        }

        // ---- PV (swapped): O'[d][q] += V^T[d][k] * P[k][q]
        short8v bP[2][2];
        #pragma unroll
        for (int qi = 0; qi < 2; ++qi) {
            int qrow = qb + qi * 16 + l15;
            bP[qi][0] = *(const short8v*)&PsT[qrow][lg * 8];
            bP[qi][1] = *(const short8v*)&PsT[qrow][32 + lg * 8];
        }
        #pragma unroll
        for (int df = 0; df < 4; ++df) {
            short8v aV0 = *(const short8v*)&Vt[cur][df * 16 + l15][lg * 8];
            short8v aV1 = *(const short8v*)&Vt[cur][df * 16 + l15][32 + lg * 8];
            #pragma unroll
            for (int qi = 0; qi < 2; ++qi) {
                o[qi][df] = __builtin_amdgcn_mfma_f32_16x16x32_bf16(aV0, bP[qi][0], o[qi][df], 0, 0, 0);
                o[qi][df] = __builtin_amdgcn_mfma_f32_16x16x32_bf16(aV1, bP[qi][1], o[qi][df], 0, 0, 0);
            }
        }

        // write next tile into the other buffer; single barrier per iteration
        if (kt < 31) {
            *(short8v*)&Ks[cur ^ 1][sr0][scq] = kreg[0];
            *(short8v*)&Ks[cur ^ 1][sr1][scq] = kreg[1];
            *(short8v*)&Vt[cur ^ 1][sr0][scq] = vreg[0];
            *(short8v*)&Vt[cur ^ 1][sr1][scq] = vreg[1];
        }
        __syncthreads();
        cur ^= 1;
    }

    // epilogue: normalize and store (4 consecutive d per packed 8B store)
    #pragma unroll
    for (int qi = 0; qi < 2; ++qi) {
        float linv = 1.0f / l_run[qi];
        size_t rowb = (size_t)(b * N_ + n0 + qb + qi * 16 + l15) * D_ + h * 64;
        #pragma unroll
        for (int df = 0; df < 4; ++df) {
            uint2 uu;
            uu.x = cvtpk_bf16(o[qi][df][0] * linv, o[qi][df][1] * linv);
            uu.y = cvtpk_bf16(o[qi][df][2] * linv, o[qi][df][3] * linv);
            *(uint2*)&attnout[rowb + df * 16 + lg * 4] = uu;
        }
    }
}

// ---------------------------------------------------------------------------
extern "C" void kernel_launch(void* const* d_in, const int* in_sizes, int n_in,
                              void* d_out, int out_size, void* d_ws, size_t ws_size,
                              hipStream_t stream) {
    const float* x      = (const float*)d_in[0];
    const float* ln1_g  = (const float*)d_in[1];
    const float* ln1_b  = (const float*)d_in[2];
    const float* Wqkv   = (const float*)d_in[3];
    const float* bqkv   = (const float*)d_in[4];
    const float* Wproj  = (const float*)d_in[5];
    const float* bproj  = (const float*)d_in[6];
    const float* ln2_g  = (const float*)d_in[7];
    const float* ln2_b  = (const float*)d_in[8];
    const float* W1     = (const float*)d_in[9];
    const float* b1     = (const float*)d_in[10];
    const float* W2     = (const float*)d_in[11];
    const float* b2     = (const float*)d_in[12];
    float* out = (float*)d_out;

    char* ws = (char*)d_ws;
    short* h_bf    = (short*)(ws + (size_t)0);
    short* qkv_bf  = (short*)(ws + ((size_t)8  << 20));
    short* vtg     = (short*)(ws + ((size_t)32 << 20));
    short* attn_bf = (short*)(ws + ((size_t)40 << 20));
    float* x2      = (float*)(ws + ((size_t)48 << 20));
    short* h2_bf   = (short*)(ws + ((size_t)64 << 20));
    short* ffh_bf  = (short*)(ws + ((size_t)72 << 20));
    short* WTqkv   = (short*)(ws + ((size_t)104 << 20));
    short* WTproj  = (short*)(ws + ((size_t)106 << 20));
    short* WT1     = (short*)(ws + ((size_t)108 << 20));
    short* WT2     = (short*)(ws + ((size_t)110 << 20));

    dim3 blk(256);

    // weight transposes (bf16)
    wt_kernel<<<dim3(24, 8),  blk, 0, stream>>>(Wqkv,  WTqkv,  512,  1536);
    wt_kernel<<<dim3(8, 8),   blk, 0, stream>>>(Wproj, WTproj, 512,  512);
    wt_kernel<<<dim3(32, 8),  blk, 0, stream>>>(W1,    WT1,    512,  2048);
    wt_kernel<<<dim3(8, 32),  blk, 0, stream>>>(W2,    WT2,    2048, 512);

    // 1. h = LN1(x)  (bf16)
    ln_bf16_kernel<<<ROWS_ / 4, blk, 0, stream>>>(x, ln1_g, ln1_b, h_bf);

    // 2. qkv = h @ Wqkv + bqkv  (bf16 out)
    gemm_bf16<false, false, true><<<dim3(12, 64), blk, 0, stream>>>(
        h_bf, WTqkv, bqkv, nullptr, nullptr, qkv_bf, ROWS_, 1536, 512);

    // 3a. V transpose per head
    vt_kernel<<<dim3(32, 32), blk, 0, stream>>>(qkv_bf, vtg);

    // 3b. attention (bf16 out)
    fattn_bf16<<<dim3(16, 32), blk, 0, stream>>>(qkv_bf, vtg, attn_bf);

    // 4. x2 = x + attn @ Wproj + bproj  (fp32 out)
    gemm_bf16<false, true, false><<<dim3(4, 64), blk, 0, stream>>>(
        attn_bf, WTproj, bproj, x, x2, nullptr, ROWS_, 512, 512);

    // 5. h2 = LN2(x2)  (bf16)
    ln_bf16_kernel<<<ROWS_ / 4, blk, 0, stream>>>(x2, ln2_g, ln2_b, h2_bf);

    // 6. ffh = gelu(h2 @ W1 + b1)  (bf16 out)
    gemm_bf16<true, false, true><<<dim3(16, 64), blk, 0, stream>>>(
        h2_bf, WT1, b1, nullptr, nullptr, ffh_bf, ROWS_, 2048, 512);

    // 7. out = x2 + ffh @ W2 + b2  (fp32 out)
    gemm_bf16<false, true, false><<<dim3(4, 64), blk, 0, stream>>>(
        ffh_bf, WT2, b2, x2, out, nullptr, ROWS_, 512, 2048);
}